// Round 2
// baseline (333.983 us; speedup 1.0000x reference)
//
#include <hip/hip_runtime.h>

typedef __attribute__((ext_vector_type(8))) short short8;
typedef __attribute__((ext_vector_type(4))) float f32x4;

#define LDA 72   // padded LDS row stride for bf16 GEMM tiles (elements)
#define KST 260  // k_kernel LDS stride (floats, 16B-aligned rows, +4-bank rotation)

__device__ __forceinline__ unsigned short f2bf(float f) {
  unsigned int u = __builtin_bit_cast(unsigned int, f);
  u += 0x7fffu + ((u >> 16) & 1u);  // RNE
  return (unsigned short)(u >> 16);
}
__device__ __forceinline__ float bf2f(unsigned short us) {
  return __builtin_bit_cast(float, (unsigned int)us << 16);
}

__device__ __forceinline__ short8 cvt8(float4 lo, float4 hi) {
  short8 v;
  v[0] = (short)f2bf(lo.x); v[1] = (short)f2bf(lo.y);
  v[2] = (short)f2bf(lo.z); v[3] = (short)f2bf(lo.w);
  v[4] = (short)f2bf(hi.x); v[5] = (short)f2bf(hi.y);
  v[6] = (short)f2bf(hi.z); v[7] = (short)f2bf(hi.w);
  return v;
}

// shared MFMA micro-kernel: 128-col B panel, A rows wm*32(+16), 64 k per call
__device__ __forceinline__ void mfma_tile(const unsigned short* __restrict__ Ab,
                                          const unsigned short* __restrict__ Bb,
                                          int wm, int wn, int lr, int lq,
                                          f32x4 (&acc)[2][4]) {
#pragma unroll
  for (int kc = 0; kc < 2; ++kc) {
    short8 a0 = *(const short8*)&Ab[(wm * 32 + lr) * LDA + kc * 32 + lq * 8];
    short8 a1 = *(const short8*)&Ab[(wm * 32 + 16 + lr) * LDA + kc * 32 + lq * 8];
#pragma unroll
    for (int ni = 0; ni < 4; ++ni) {
      short8 b = *(const short8*)&Bb[(wn * 64 + ni * 16 + lr) * LDA + kc * 32 + lq * 8];
      acc[0][ni] = __builtin_amdgcn_mfma_f32_16x16x32_bf16(a0, b, acc[0][ni], 0, 0, 0);
      acc[1][ni] = __builtin_amdgcn_mfma_f32_16x16x32_bf16(a1, b, acc[1][ni], 0, 0, 0);
    }
  }
}

// ---------------- prep: all weight conversions in one launch ----------------
__device__ __forceinline__ void cvt_block(const float* __restrict__ src,
                                          unsigned short* __restrict__ dst, int b) {
  int i = b * 256 + threadIdx.x;
  float4 f = ((const float4*)src)[i];
  unsigned int lo = (unsigned int)f2bf(f.x) | ((unsigned int)f2bf(f.y) << 16);
  unsigned int hi = (unsigned int)f2bf(f.z) | ((unsigned int)f2bf(f.w) << 16);
  uint2 u; u.x = lo; u.y = hi;
  ((uint2*)dst)[i] = u;
}

__global__ __launch_bounds__(256) void prep_kernel(
    const float* __restrict__ W_embed, const float* __restrict__ Wout,
    const float* __restrict__ Wv, const float* __restrict__ Wq,
    unsigned short* __restrict__ Wb, unsigned short* __restrict__ Wob,
    unsigned short* __restrict__ Wvb, float* __restrict__ WqR) {
  int b = blockIdx.x;
  if (b < 1024) { cvt_block(W_embed, Wb, b); return; }
  if (b < 2048) { cvt_block(Wout, Wob, b - 1024); return; }
  if (b < 2112) { cvt_block(Wv, Wvb, b - 2048); return; }
  // WqR[h][e] = mean_j Wq[h*64+j][e]
  int idx = (b - 2112) * 256 + threadIdx.x;  // 0..1023
  int h = idx >> 8, e = idx & 255;
  float s = 0.f;
  for (int j = 0; j < 64; ++j) s += Wq[(size_t)(h * 64 + j) * 256 + e];
  WqR[idx] = s * (1.f / 64.f);
}

// ---------------- GEMM1 (split-K): part[s] = patches @ W_embed^T (K-chunk s) ----------------
// M=8192, N=256, K=4096 split 4x1024. Tile 128x128, BK=64, 512 threads (8 waves),
// grid (2,64,4). TWO-deep register prefetch + double-buffered LDS: a tile's global
// loads are issued two MFMA-phases (~800+ cy) before their convert/ds_write, so the
// ~900 cy HBM latency is fully covered (1-deep only covered ~300 cy).
struct StageG1 { float4 a0, a1, a2, a3; short8 b0, b1; };

__device__ __forceinline__ void g1_load(StageG1& s, const float* q0, const float* q1,
                                        const unsigned short* b0, const unsigned short* b1) {
  s.a0 = *(const float4*)q0; s.a1 = *(const float4*)(q0 + 4);
  s.a2 = *(const float4*)q1; s.a3 = *(const float4*)(q1 + 4);
  s.b0 = *(const short8*)b0; s.b1 = *(const short8*)b1;
}

__device__ __forceinline__ void g1_write(unsigned short* Aw, unsigned short* Bw,
                                         int dA0, int dA1, int dB0, int dB1,
                                         const StageG1& s) {
  *(short8*)&Aw[dA0] = cvt8(s.a0, s.a1);
  *(short8*)&Aw[dA1] = cvt8(s.a2, s.a3);
  *(short8*)&Bw[dB0] = s.b0;
  *(short8*)&Bw[dB1] = s.b1;
}

__global__ __launch_bounds__(512, 4) void gemm1_embed(
    const float* __restrict__ x, const unsigned short* __restrict__ Wb,
    float* __restrict__ part) {
  // [buf][A=0/B=1][128*LDA] bf16 -> 73728 B total, 2 blocks/CU
  __shared__ __align__(16) unsigned short sm[2][2][128 * LDA];
  const int nt = blockIdx.x, mt = blockIdx.y, sk = blockIdx.z;
  const int m0 = mt * 128, n0 = nt * 128;
  const int t = threadIdx.x;
  const int wave = t >> 6, lane = t & 63;
  const int wm = wave >> 1, wn = wave & 1;        // 4x2 wave grid -> 32x64 per wave
  const int lr = lane & 15, lq = lane >> 4;

  const int bn = m0 >> 10;                         // batch (tile never crosses)
  const int ph0 = (m0 & 1023) >> 5;                // first patch-row of tile (mult of 4)

  // A staging: per tile, A-chunk = 32 consecutive image rows of 1KB (one channel).
  const int uA0 = t >> 5, colA = t & 31;
  const int uA1 = uA0 + 16;
  const float* xA = x + ((size_t)(bn << 6) << 16);  // channel plane stride 65536 floats
  const float* pa0 = xA + (size_t)(((ph0 + (uA0 >> 3)) << 3) + (uA0 & 7)) * 256 + (colA << 3);
  const float* pa1 = xA + (size_t)(((ph0 + (uA1 >> 3)) << 3) + (uA1 & 7)) * 256 + (colA << 3);
  const int dA0 = (((uA0 >> 3) << 5) + colA) * LDA + ((uA0 & 7) << 3);
  const int dA1 = (((uA1 >> 3) << 5) + colA) * LDA + ((uA1 & 7) << 3);

  // B staging: 128 rows x 64 k bf16 = 16KB
  const int nB0 = t >> 3, kB = t & 7;
  const int nB1 = nB0 + 64;
  const unsigned short* pb0 = Wb + (size_t)(n0 + nB0) * 4096 + (kB << 3);
  const unsigned short* pb1 = Wb + (size_t)(n0 + nB1) * 4096 + (kB << 3);
  const int dB0 = nB0 * LDA + (kB << 3);
  const int dB1 = nB1 * LDA + (kB << 3);

  f32x4 acc[2][4];
#pragma unroll
  for (int i = 0; i < 2; i++)
#pragma unroll
    for (int j = 0; j < 4; j++) acc[i][j] = f32x4{0.f, 0.f, 0.f, 0.f};

  unsigned short* A0 = &sm[0][0][0]; unsigned short* B0 = &sm[0][1][0];
  unsigned short* A1 = &sm[1][0][0]; unsigned short* B1 = &sm[1][1][0];

  StageG1 st0, st1;
  const int kt0 = sk * 16;
  // prologue: 2 tiles in flight, tile 0 written to buf0
  g1_load(st0, pa0 + (size_t)kt0 * 65536, pa1 + (size_t)kt0 * 65536,
          pb0 + (size_t)kt0 * 64, pb1 + (size_t)kt0 * 64);
  g1_load(st1, pa0 + (size_t)(kt0 + 1) * 65536, pa1 + (size_t)(kt0 + 1) * 65536,
          pb0 + (size_t)(kt0 + 1) * 64, pb1 + (size_t)(kt0 + 1) * 64);
  g1_write(A0, B0, dA0, dA1, dB0, dB1, st0);
  __syncthreads();

#pragma unroll 1
  for (int p = 0; p < 7; ++p) {
    const int kb = kt0 + 2 * p;
    // phase A: compute tile 2p (buf0); st0 refilled with tile 2p+2
    g1_load(st0, pa0 + (size_t)(kb + 2) * 65536, pa1 + (size_t)(kb + 2) * 65536,
            pb0 + (size_t)(kb + 2) * 64, pb1 + (size_t)(kb + 2) * 64);
    mfma_tile(A0, B0, wm, wn, lr, lq, acc);
    g1_write(A1, B1, dA0, dA1, dB0, dB1, st1);   // st1 = tile 2p+1, loaded 2 phases ago
    __syncthreads();
    // phase B: compute tile 2p+1 (buf1); st1 refilled with tile 2p+3
    g1_load(st1, pa0 + (size_t)(kb + 3) * 65536, pa1 + (size_t)(kb + 3) * 65536,
            pb0 + (size_t)(kb + 3) * 64, pb1 + (size_t)(kb + 3) * 64);
    mfma_tile(A1, B1, wm, wn, lr, lq, acc);
    g1_write(A0, B0, dA0, dA1, dB0, dB1, st0);   // st0 = tile 2p+2
    __syncthreads();
  }
  // tail: tiles 14, 15 (no more loads)
  mfma_tile(A0, B0, wm, wn, lr, lq, acc);
  g1_write(A1, B1, dA0, dA1, dB0, dB1, st1);
  __syncthreads();
  mfma_tile(A1, B1, wm, wn, lr, lq, acc);

  float* pdst = part + (size_t)sk * 2097152;
#pragma unroll
  for (int mi = 0; mi < 2; ++mi)
#pragma unroll
    for (int ni = 0; ni < 4; ++ni) {
      int col = n0 + wn * 64 + ni * 16 + lr;
      int rbase = m0 + wm * 32 + mi * 16 + lq * 4;
#pragma unroll
      for (int r2 = 0; r2 < 4; ++r2)
        pdst[(size_t)(rbase + r2) * 256 + col] = acc[mi][ni][r2];
    }
}

// ---------------- finq: emb_bf = bf16(sum parts + b + pos); q fused ----------------
// grid 256 blocks, 32 rows/block, 8 threads/row (32 cols each).
__global__ __launch_bounds__(256) void finq_kernel(
    const float* __restrict__ part, const float* __restrict__ b_embed,
    const float* __restrict__ pos, const float* __restrict__ WqR,
    unsigned short* __restrict__ emb_bf, float* __restrict__ q) {
  __shared__ float wq[1024];
  const int t = threadIdx.x;
  for (int i = t; i < 1024; i += 256) wq[i] = WqR[i];
  __syncthreads();
  const int row_l = t >> 3, seg = t & 7;
  const int row = blockIdx.x * 32 + row_l;
  const int bn = row >> 10, n = row & 1023;
  const float4* p4 = (const float4*)part;
  const float4* b4 = (const float4*)b_embed;
  const float4* pos4 = (const float4*)pos;
  const float4* wq4 = (const float4*)wq;
  const int idx0 = row * 64 + seg * 8;

  float4 e[8];
#pragma unroll
  for (int j = 0; j < 8; ++j) {
    float4 v = p4[idx0 + j];
    float4 v1 = p4[524288 + idx0 + j];
    float4 v2 = p4[1048576 + idx0 + j];
    float4 v3 = p4[1572864 + idx0 + j];
    float4 bb = b4[seg * 8 + j];
    float4 pp = pos4[(size_t)n * 64 + seg * 8 + j];
    e[j].x = v.x + v1.x + v2.x + v3.x + bb.x + pp.x;
    e[j].y = v.y + v1.y + v2.y + v3.y + bb.y + pp.y;
    e[j].z = v.z + v1.z + v2.z + v3.z + bb.z + pp.z;
    e[j].w = v.w + v1.w + v2.w + v3.w + bb.w + pp.w;
  }
  // bf16 write (32 floats -> 4 uint4)
  unsigned int ub[16];
#pragma unroll
  for (int j = 0; j < 8; ++j) {
    ub[2 * j]     = (unsigned int)f2bf(e[j].x) | ((unsigned int)f2bf(e[j].y) << 16);
    ub[2 * j + 1] = (unsigned int)f2bf(e[j].z) | ((unsigned int)f2bf(e[j].w) << 16);
  }
  uint4* dst = (uint4*)(emb_bf + (size_t)row * 256 + seg * 32);
#pragma unroll
  for (int j = 0; j < 4; ++j)
    dst[j] = make_uint4(ub[4 * j], ub[4 * j + 1], ub[4 * j + 2], ub[4 * j + 3]);
  // q: dot with head-reduced Wq
  float s[4] = {0.f, 0.f, 0.f, 0.f};
#pragma unroll
  for (int h = 0; h < 4; ++h)
#pragma unroll
    for (int j = 0; j < 8; ++j) {
      float4 w = wq4[h * 64 + seg * 8 + j];
      s[h] += e[j].x * w.x + e[j].y * w.y + e[j].z * w.z + e[j].w * w.w;
    }
#pragma unroll
  for (int h = 0; h < 4; ++h) {
    s[h] += __shfl_xor(s[h], 1);
    s[h] += __shfl_xor(s[h], 2);
    s[h] += __shfl_xor(s[h], 4);
  }
  if (seg == 0) {
#pragma unroll
    for (int h = 0; h < 4; ++h)
      q[(size_t)(bn * 4 + h) * 1024 + n] = s[h];
  }
}

// ---------------- kk[bh][m] = sigmoid(q[bh] . Wk[m]) ----------------
// grid 128 (8 m-rows per block), thread = (m = t&7, bh = t>>3).
__global__ __launch_bounds__(256) void k_kernel(const float* __restrict__ q,
                                                const float* __restrict__ Wk,
                                                float* __restrict__ kk) {
  __shared__ float wk_s[8 * KST];
  __shared__ float q_s[32 * KST];
  const int m0 = blockIdx.x * 8;
  const int t = threadIdx.x;
  const int m = t & 7, bh = t >> 3;
  const float4* wkg = (const float4*)Wk;
  const float4* qg = (const float4*)q;
  float acc = 0.f;
  for (int kt = 0; kt < 4; ++kt) {
    const int k0 = kt * 256;
#pragma unroll
    for (int i = 0; i < 2; ++i) {
      int idx = t + i * 256;
      int r = idx >> 6, c4 = idx & 63;
      *(float4*)&wk_s[r * KST + c4 * 4] = wkg[((size_t)(m0 + r) * 1024 + k0) / 4 + c4];
    }
#pragma unroll
    for (int i = 0; i < 8; ++i) {
      int idx = t + i * 256;
      int r = idx >> 6, c4 = idx & 63;
      *(float4*)&q_s[r * KST + c4 * 4] = qg[((size_t)r * 1024 + k0) / 4 + c4];
    }
    __syncthreads();
#pragma unroll 8
    for (int k4 = 0; k4 < 64; ++k4) {
      float4 a = *(const float4*)&wk_s[m * KST + k4 * 4];
      float4 b = *(const float4*)&q_s[bh * KST + k4 * 4];
      acc += a.x * b.x + a.y * b.y + a.z * b.z + a.w * b.w;
    }
    __syncthreads();
  }
  kk[(size_t)bh * 1024 + m0 + m] = 1.f / (1.f + __expf(-acc));
}

// ---------------- vgemm: ov = bf16( (emb_bf @ Wv^T) * gate ) ----------------
// M=8192, N=256, K=256. Tile 64x64, single-shot K (whole panel in LDS, ONE barrier).
// grid (4,128), 2 blocks/CU; 16 independent 16B loads in flight per thread.
#define VST 264
__global__ __launch_bounds__(256) void vgemm_kernel(
    const unsigned short* __restrict__ Abf, const unsigned short* __restrict__ Wvb,
    const float* __restrict__ kk, unsigned short* __restrict__ ov) {
  __shared__ __align__(16) unsigned short Vs[128 * VST];  // 67584 B
  const int nt = blockIdx.x, mt = blockIdx.y;
  const int m0 = mt * 64, n0 = nt * 64;
  const int t = threadIdx.x;
  const int wave = t >> 6, lane = t & 63;
  const int wr = wave >> 1, wc = wave & 1;
  const int lr = lane & 15, lq = lane >> 4;

  const int row0 = t >> 5, kb = t & 31;  // slot: row = row0 + i*8, 16B unit kb
#pragma unroll
  for (int i = 0; i < 8; ++i)
    *(short8*)&Vs[(row0 + i * 8) * VST + kb * 8] =
        *(const short8*)(Abf + (size_t)(m0 + row0 + i * 8) * 256 + kb * 8);
#pragma unroll
  for (int i = 0; i < 8; ++i)
    *(short8*)&Vs[(64 + row0 + i * 8) * VST + kb * 8] =
        *(const short8*)(Wvb + (size_t)(n0 + row0 + i * 8) * 256 + kb * 8);
  __syncthreads();

  f32x4 acc[2][2];
#pragma unroll
  for (int i = 0; i < 2; ++i)
#pragma unroll
    for (int j = 0; j < 2; ++j) acc[i][j] = f32x4{0.f, 0.f, 0.f, 0.f};

#pragma unroll
  for (int kc = 0; kc < 8; ++kc) {
    short8 a0 = *(const short8*)&Vs[(wr * 32 + lr) * VST + kc * 32 + lq * 8];
    short8 a1 = *(const short8*)&Vs[(wr * 32 + 16 + lr) * VST + kc * 32 + lq * 8];
    short8 b0 = *(const short8*)&Vs[(64 + wc * 32 + lr) * VST + kc * 32 + lq * 8];
    short8 b1 = *(const short8*)&Vs[(64 + wc * 32 + 16 + lr) * VST + kc * 32 + lq * 8];
    acc[0][0] = __builtin_amdgcn_mfma_f32_16x16x32_bf16(a0, b0, acc[0][0], 0, 0, 0);
    acc[0][1] = __builtin_amdgcn_mfma_f32_16x16x32_bf16(a0, b1, acc[0][1], 0, 0, 0);
    acc[1][0] = __builtin_amdgcn_mfma_f32_16x16x32_bf16(a1, b0, acc[1][0], 0, 0, 0);
    acc[1][1] = __builtin_amdgcn_mfma_f32_16x16x32_bf16(a1, b1, acc[1][1], 0, 0, 0);
  }

#pragma unroll
  for (int mi = 0; mi < 2; ++mi)
#pragma unroll
    for (int ni = 0; ni < 2; ++ni) {
      int col = n0 + wc * 32 + ni * 16 + lr;
      int h = col >> 6;
      int rbase = m0 + wr * 32 + mi * 16 + lq * 4;
#pragma unroll
      for (int r2 = 0; r2 < 4; ++r2) {
        int row = rbase + r2;
        int bn = row >> 10, n = row & 1023;
        float g = kk[(size_t)(bn * 4 + h) * 1024 + n];
        ov[(size_t)row * 256 + col] = f2bf(acc[mi][ni][r2] * g);
      }
    }
}

// ---------------- GEMM2: out = ov @ Wout^T + b_out, folded, coalesced ----------------
// M=8192, N=4096, K=256. Tile 64x128, grid (32,128). Reg-prefetch double-buffered
// K-pipeline (4 tiles, fully peeled), LDS 55KB -> 2 blocks/CU. LDS-transposed epilogue.
#define CST 132  // epilogue C_s stride (floats)
struct StageG2 { short8 a[2]; short8 b[4]; };

__device__ __forceinline__ void g2_load(StageG2& s, const unsigned short* pA,
                                        const unsigned short* pB, int k0) {
#pragma unroll
  for (int i = 0; i < 2; ++i)
    s.a[i] = *(const short8*)(pA + (size_t)i * 32 * 256 + k0);
#pragma unroll
  for (int i = 0; i < 4; ++i)
    s.b[i] = *(const short8*)(pB + (size_t)i * 32 * 256 + k0);
}
__device__ __forceinline__ void g2_write(unsigned short* Ab, unsigned short* Bb,
                                         int dA, int dB, const StageG2& s) {
#pragma unroll
  for (int i = 0; i < 2; ++i) *(short8*)&Ab[dA + i * 32 * LDA] = s.a[i];
#pragma unroll
  for (int i = 0; i < 4; ++i) *(short8*)&Bb[dB + i * 32 * LDA] = s.b[i];
}

__global__ __launch_bounds__(256, 2) void gemm2_out(
    const unsigned short* __restrict__ Abf, const unsigned short* __restrict__ Wob,
    const float* __restrict__ b_out, float* __restrict__ out) {
  __shared__ __align__(16) unsigned short smbuf[2][192 * LDA];  // 55296 B
  float* csm = (float*)&smbuf[0][0];                            // epilogue aliases (33792 B)
  const int nt = blockIdx.x, mt = blockIdx.y;
  const int m0 = mt * 64, n0 = nt * 128;
  const int t = threadIdx.x;
  const int wave = t >> 6, lane = t & 63;
  const int wm = wave >> 1, wn = wave & 1;
  const int lr = lane & 15, lq = lane >> 4;

  unsigned short* A0 = &smbuf[0][0]; unsigned short* B0 = &smbuf[0][64 * LDA];
  unsigned short* A1 = &smbuf[1][0]; unsigned short* B1 = &smbuf[1][64 * LDA];

  const unsigned short* pA = Abf + (size_t)(m0 + (t >> 3)) * 256 + (t & 7) * 8;
  const unsigned short* pB = Wob + (size_t)(n0 + (t >> 3)) * 256 + (t & 7) * 8;
  const int dA = (t >> 3) * LDA + (t & 7) * 8;
  const int dB = dA;

  f32x4 acc[2][4];
#pragma unroll
  for (int i = 0; i < 2; i++)
#pragma unroll
    for (int j = 0; j < 4; j++) acc[i][j] = f32x4{0.f, 0.f, 0.f, 0.f};

  StageG2 st0, st1;
  g2_load(st0, pA, pB, 0);
  g2_load(st1, pA, pB, 64);
  g2_write(A0, B0, dA, dB, st0);
  __syncthreads();
  g2_load(st0, pA, pB, 128);
  mfma_tile(A0, B0, wm, wn, lr, lq, acc);
  g2_write(A1, B1, dA, dB, st1);
  __syncthreads();
  g2_load(st1, pA, pB, 192);
  mfma_tile(A1, B1, wm, wn, lr, lq, acc);
  g2_write(A0, B0, dA, dB, st0);
  __syncthreads();
  mfma_tile(A0, B0, wm, wn, lr, lq, acc);
  g2_write(A1, B1, dA, dB, st1);
  __syncthreads();
  mfma_tile(A1, B1, wm, wn, lr, lq, acc);
  __syncthreads();  // all reads done before epilogue aliases LDS

  // stage C tile into LDS [m_local][p_local]
#pragma unroll
  for (int mi = 0; mi < 2; ++mi)
#pragma unroll
    for (int ni = 0; ni < 4; ++ni) {
      int pl = wn * 64 + ni * 16 + lr;
      int mb = wm * 32 + mi * 16 + lq * 4;
#pragma unroll
      for (int r2 = 0; r2 < 4; ++r2)
        csm[(mb + r2) * CST + pl] = acc[mi][ni][r2];
    }
  __syncthreads();
  // coalesced folded write: tile = 2 contiguous 16 KiB runs (one per c2)
  const int bn = m0 >> 10;
  const int ph0 = (m0 & 1023) >> 5;
  const int c0 = n0 >> 6;
#pragma unroll
  for (int i = 0; i < 8; ++i) {
    int idx4 = t + i * 256;                  // 0..2047 float4s
    int kw4 = idx4 & 1;
    int pw = (idx4 >> 1) & 31;
    int kh = (idx4 >> 6) & 7;
    int c2 = (idx4 >> 9) & 1;
    int ph = (idx4 >> 10) & 1;
    int m_local = ph * 32 + pw;
    int p_local = c2 * 64 + kh * 8 + kw4 * 4;
    float4 v = *(const float4*)&csm[m_local * CST + p_local];
    float4 bo = *(const float4*)(b_out + n0 + p_local);
    v.x += bo.x; v.y += bo.y; v.z += bo.z; v.w += bo.w;
    size_t addr = ((size_t)((bn << 6) + c0 + c2) << 16) +
                  (size_t)(((ph0 + ph) << 3) + kh) * 256 + (pw << 3) + kw4 * 4;
    *(float4*)(out + addr) = v;
  }
}

extern "C" void kernel_launch(void* const* d_in, const int* in_sizes, int n_in,
                              void* d_out, int out_size, void* d_ws, size_t ws_size,
                              hipStream_t stream) {
  const float* x       = (const float*)d_in[0];
  const float* W_embed = (const float*)d_in[1];
  const float* b_embed = (const float*)d_in[2];
  const float* pos     = (const float*)d_in[3];
  const float* Wq      = (const float*)d_in[4];
  const float* Wk      = (const float*)d_in[5];
  const float* Wv      = (const float*)d_in[6];
  const float* Wout    = (const float*)d_in[7];
  const float* b_out   = (const float*)d_in[8];
  float* out = (float*)d_out;

  char* ws = (char*)d_ws;
  const size_t MB = 1024 * 1024;
  float* part            = (float*)(ws);                      // 32 MiB (4 x 8 MiB)
  unsigned short* ov     = (unsigned short*)(ws);             // 4 MiB, aliases part (dead by then)
  unsigned short* emb_bf = (unsigned short*)(ws + 32 * MB);   // 4 MiB
  unsigned short* Wb     = (unsigned short*)(ws + 36 * MB);   // 2 MiB
  unsigned short* Wob    = (unsigned short*)(ws + 38 * MB);   // 2 MiB
  unsigned short* Wvb    = (unsigned short*)(ws + 40 * MB);   // 128 KiB
  float* q               = (float*)(ws + 40 * MB + 131072);   // 128 KiB
  float* kk              = (float*)(ws + 40 * MB + 262144);   // 128 KiB
  float* WqR             = (float*)(ws + 40 * MB + 393216);   // 4 KiB

  prep_kernel<<<2116, 256, 0, stream>>>(W_embed, Wout, Wv, Wq, Wb, Wob, Wvb, WqR);
  gemm1_embed<<<dim3(2, 64, 4), 512, 0, stream>>>(x, Wb, part);
  finq_kernel<<<256, 256, 0, stream>>>(part, b_embed, pos, WqR, emb_bf, q);
  k_kernel<<<128, 256, 0, stream>>>(q, Wk, kk);
  vgemm_kernel<<<dim3(4, 128), 256, 0, stream>>>(emb_bf, Wvb, kk, ov);
  gemm2_out<<<dim3(32, 128), 256, 0, stream>>>(ov, Wob, b_out, out);
}

// Round 3
// 323.181 us; speedup vs baseline: 1.0334x; 1.0334x over previous
//
#include <hip/hip_runtime.h>

typedef __attribute__((ext_vector_type(8))) short short8;
typedef __attribute__((ext_vector_type(4))) float f32x4;

#define LDA 72   // padded LDS row stride for bf16 GEMM tiles (elements)
#define KST 260  // k_kernel LDS stride (floats, 16B-aligned rows, +4-bank rotation)

__device__ __forceinline__ unsigned short f2bf(float f) {
  unsigned int u = __builtin_bit_cast(unsigned int, f);
  u += 0x7fffu + ((u >> 16) & 1u);  // RNE
  return (unsigned short)(u >> 16);
}
__device__ __forceinline__ float bf2f(unsigned short us) {
  return __builtin_bit_cast(float, (unsigned int)us << 16);
}

__device__ __forceinline__ short8 cvt8(float4 lo, float4 hi) {
  short8 v;
  v[0] = (short)f2bf(lo.x); v[1] = (short)f2bf(lo.y);
  v[2] = (short)f2bf(lo.z); v[3] = (short)f2bf(lo.w);
  v[4] = (short)f2bf(hi.x); v[5] = (short)f2bf(hi.y);
  v[6] = (short)f2bf(hi.z); v[7] = (short)f2bf(hi.w);
  return v;
}

// shared MFMA micro-kernel: A rows wm*32(+16), B cols wn*64..+64, 64 k per call
__device__ __forceinline__ void mfma_tile(const unsigned short* __restrict__ Ab,
                                          const unsigned short* __restrict__ Bb,
                                          int wm, int wn, int lr, int lq,
                                          f32x4 (&acc)[2][4]) {
#pragma unroll
  for (int kc = 0; kc < 2; ++kc) {
    short8 a0 = *(const short8*)&Ab[(wm * 32 + lr) * LDA + kc * 32 + lq * 8];
    short8 a1 = *(const short8*)&Ab[(wm * 32 + 16 + lr) * LDA + kc * 32 + lq * 8];
#pragma unroll
    for (int ni = 0; ni < 4; ++ni) {
      short8 b = *(const short8*)&Bb[(wn * 64 + ni * 16 + lr) * LDA + kc * 32 + lq * 8];
      acc[0][ni] = __builtin_amdgcn_mfma_f32_16x16x32_bf16(a0, b, acc[0][ni], 0, 0, 0);
      acc[1][ni] = __builtin_amdgcn_mfma_f32_16x16x32_bf16(a1, b, acc[1][ni], 0, 0, 0);
    }
  }
}

// ---------------- prep: all weight conversions in one launch ----------------
__device__ __forceinline__ void cvt_block(const float* __restrict__ src,
                                          unsigned short* __restrict__ dst, int b) {
  int i = b * 256 + threadIdx.x;
  float4 f = ((const float4*)src)[i];
  unsigned int lo = (unsigned int)f2bf(f.x) | ((unsigned int)f2bf(f.y) << 16);
  unsigned int hi = (unsigned int)f2bf(f.z) | ((unsigned int)f2bf(f.w) << 16);
  uint2 u; u.x = lo; u.y = hi;
  ((uint2*)dst)[i] = u;
}

__global__ __launch_bounds__(256) void prep_kernel(
    const float* __restrict__ W_embed, const float* __restrict__ Wout,
    const float* __restrict__ Wv, const float* __restrict__ Wq,
    unsigned short* __restrict__ Wb, unsigned short* __restrict__ Wob,
    unsigned short* __restrict__ Wvb, float* __restrict__ WqR) {
  int b = blockIdx.x;
  if (b < 1024) { cvt_block(W_embed, Wb, b); return; }
  if (b < 2048) { cvt_block(Wout, Wob, b - 1024); return; }
  if (b < 2112) { cvt_block(Wv, Wvb, b - 2048); return; }
  // WqR[h][e] = mean_j Wq[h*64+j][e]
  int idx = (b - 2112) * 256 + threadIdx.x;  // 0..1023
  int h = idx >> 8, e = idx & 255;
  float s = 0.f;
  for (int j = 0; j < 64; ++j) s += Wq[(size_t)(h * 64 + j) * 256 + e];
  WqR[idx] = s * (1.f / 64.f);
}

// ---------------- gemm1_fused: emb_bf = bf16(patches @ W_embed^T + b + pos), q fused ----
// M=8192, N=256 (FULL), K=4096. Tile 32x256, BK=64, 256 threads (4 waves, wave = 32x64),
// grid 256 (1 block/CU). 2-deep reg-prefetch double-buffered LDS. No split-K: kills the
// 32MB part write + 128MB part re-read, and finq folds into the epilogue (emb rows are
// complete per block, so q is an in-block 256-dot -- no atomics).
struct StageV3 { float4 a0, a1; short8 b[8]; };

__global__ __launch_bounds__(256, 1) void gemm1_fused(
    const float* __restrict__ x, const unsigned short* __restrict__ Wb,
    const float* __restrict__ b_embed, const float* __restrict__ pos,
    const float* __restrict__ WqR,
    unsigned short* __restrict__ emb_bf, float* __restrict__ q) {
  // A0 A1 (32*72 each) | B0 B1 (256*72 each) = 41472 shorts = 82944 B
  __shared__ __align__(16) unsigned short lds[41472];
  __shared__ float wq_s[1024];
  unsigned short* A0 = lds;
  unsigned short* A1 = lds + 2304;
  unsigned short* B0 = lds + 4608;
  unsigned short* B1 = lds + 23040;
  float* esm = (float*)(lds + 4608);  // epilogue 32x264 fp32 = 33792 B, aliases B0 only

  const int t = threadIdx.x;
  const int wave = t >> 6, lane = t & 63;
  const int wn = wave;                 // 4 waves across N (cols wn*64..+64)
  const int lr = lane & 15, lq = lane >> 4;
  const int m0 = blockIdx.x * 32;
  const int bn = m0 >> 10;             // batch index (tile never crosses)
  const int nbase = m0 & 1023;         // patch index base; mult of 32 -> ph fixed, pw = row
  const int ph = nbase >> 5;

  for (int i = t; i < 1024; i += 256) wq_s[i] = WqR[i];

  // A: per iter 32 rows x 64 k fp32 (one channel c=kt). thread: row mA, k-cell kc8.
  const int mA = t >> 3, kc8 = t & 7;
  const float* pa = x + ((size_t)(bn << 6) << 16) +
                    (size_t)((ph << 3) + kc8) * 256 + (mA << 3);
  const int dA = mA * LDA + (kc8 << 3);
  // B: per iter 256 rows x 64 k bf16; thread covers rows (t>>3)+{0,32,..,224}, cell t&7.
  const unsigned short* pb = Wb + (size_t)(t >> 3) * 4096 + ((t & 7) << 3);
  const int dB = (t >> 3) * LDA + ((t & 7) << 3);

  f32x4 acc[2][4];
#pragma unroll
  for (int i = 0; i < 2; i++)
#pragma unroll
    for (int j = 0; j < 4; j++) acc[i][j] = f32x4{0.f, 0.f, 0.f, 0.f};

  StageV3 st0, st1;
  // load(kt): A 2x float4 + B 8x short8 (10 loads in flight per stage)
#define G1F_LOAD(st, kt)                                                         \
  {                                                                              \
    const float* qa = pa + (size_t)(kt) * 65536;                                 \
    st.a0 = *(const float4*)qa; st.a1 = *(const float4*)(qa + 4);                \
    _Pragma("unroll")                                                            \
    for (int i = 0; i < 8; ++i)                                                  \
      st.b[i] = *(const short8*)(pb + (size_t)i * 131072 + (kt) * 64);           \
  }
#define G1F_WRITE(st, Aw, Bw)                                                    \
  {                                                                              \
    *(short8*)&Aw[dA] = cvt8(st.a0, st.a1);                                      \
    _Pragma("unroll")                                                            \
    for (int i = 0; i < 8; ++i) *(short8*)&Bw[dB + i * 32 * LDA] = st.b[i];      \
  }

  G1F_LOAD(st0, 0)
  G1F_LOAD(st1, 1)
  G1F_WRITE(st0, A0, B0)
  __syncthreads();

#pragma unroll 1
  for (int p = 0; p < 31; ++p) {
    G1F_LOAD(st0, 2 * p + 2)
    mfma_tile(A0, B0, 0, wn, lr, lq, acc);
    G1F_WRITE(st1, A1, B1)
    __syncthreads();
    G1F_LOAD(st1, 2 * p + 3)
    mfma_tile(A1, B1, 0, wn, lr, lq, acc);
    G1F_WRITE(st0, A0, B0)
    __syncthreads();
  }
  // tail: tiles 62, 63
  mfma_tile(A0, B0, 0, wn, lr, lq, acc);
  G1F_WRITE(st1, A1, B1)
  __syncthreads();
  mfma_tile(A1, B1, 0, wn, lr, lq, acc);
  // esm aliases B0 (last read of B0 was before the barrier above); B1/A untouched.

  // stage emb tile (raw acc) into LDS [row][col], 264-f stride
#pragma unroll
  for (int mi = 0; mi < 2; ++mi)
#pragma unroll
    for (int ni = 0; ni < 4; ++ni) {
      int col = wn * 64 + ni * 16 + lr;
      int rb = mi * 16 + lq * 4;
#pragma unroll
      for (int r2 = 0; r2 < 4; ++r2)
        esm[(rb + r2) * 264 + col] = acc[mi][ni][r2];
    }
  __syncthreads();

  // finq body: 8 threads/row, 32 cols each. e = acc + bias + pos; write bf16; q-dot.
  {
    const int row = t >> 3, seg = t & 7;
    const int n = nbase + row;
    const float4* e4 = (const float4*)esm;
    const float4* b4 = (const float4*)b_embed;
    const float4* pos4 = (const float4*)pos;
    const float4* wq4 = (const float4*)wq_s;
    float4 e[8];
#pragma unroll
    for (int j = 0; j < 8; ++j) {
      float4 v = e4[row * 66 + seg * 8 + j];
      float4 bb = b4[seg * 8 + j];
      float4 pp = pos4[(size_t)n * 64 + seg * 8 + j];
      e[j].x = v.x + bb.x + pp.x;
      e[j].y = v.y + bb.y + pp.y;
      e[j].z = v.z + bb.z + pp.z;
      e[j].w = v.w + bb.w + pp.w;
    }
    unsigned int ub[16];
#pragma unroll
    for (int j = 0; j < 8; ++j) {
      ub[2 * j]     = (unsigned int)f2bf(e[j].x) | ((unsigned int)f2bf(e[j].y) << 16);
      ub[2 * j + 1] = (unsigned int)f2bf(e[j].z) | ((unsigned int)f2bf(e[j].w) << 16);
    }
    uint4* dst = (uint4*)(emb_bf + (size_t)(m0 + row) * 256 + seg * 32);
#pragma unroll
    for (int j = 0; j < 4; ++j)
      dst[j] = make_uint4(ub[4 * j], ub[4 * j + 1], ub[4 * j + 2], ub[4 * j + 3]);
    float s[4] = {0.f, 0.f, 0.f, 0.f};
#pragma unroll
    for (int h = 0; h < 4; ++h)
#pragma unroll
      for (int j = 0; j < 8; ++j) {
        float4 w = wq4[h * 64 + seg * 8 + j];
        s[h] += e[j].x * w.x + e[j].y * w.y + e[j].z * w.z + e[j].w * w.w;
      }
#pragma unroll
    for (int h = 0; h < 4; ++h) {
      s[h] += __shfl_xor(s[h], 1);
      s[h] += __shfl_xor(s[h], 2);
      s[h] += __shfl_xor(s[h], 4);
    }
    if (seg == 0) {
#pragma unroll
      for (int h = 0; h < 4; ++h)
        q[(size_t)(bn * 4 + h) * 1024 + n] = s[h];
    }
  }
#undef G1F_LOAD
#undef G1F_WRITE
}

// ---------------- kk[bh][m] = sigmoid(q[bh] . Wk[m]) ----------------
// grid 128 (8 m-rows per block), thread = (m = t&7, bh = t>>3).
__global__ __launch_bounds__(256) void k_kernel(const float* __restrict__ q,
                                                const float* __restrict__ Wk,
                                                float* __restrict__ kk) {
  __shared__ float wk_s[8 * KST];
  __shared__ float q_s[32 * KST];
  const int m0 = blockIdx.x * 8;
  const int t = threadIdx.x;
  const int m = t & 7, bh = t >> 3;
  const float4* wkg = (const float4*)Wk;
  const float4* qg = (const float4*)q;
  float acc = 0.f;
  for (int kt = 0; kt < 4; ++kt) {
    const int k0 = kt * 256;
#pragma unroll
    for (int i = 0; i < 2; ++i) {
      int idx = t + i * 256;
      int r = idx >> 6, c4 = idx & 63;
      *(float4*)&wk_s[r * KST + c4 * 4] = wkg[((size_t)(m0 + r) * 1024 + k0) / 4 + c4];
    }
#pragma unroll
    for (int i = 0; i < 8; ++i) {
      int idx = t + i * 256;
      int r = idx >> 6, c4 = idx & 63;
      *(float4*)&q_s[r * KST + c4 * 4] = qg[((size_t)r * 1024 + k0) / 4 + c4];
    }
    __syncthreads();
#pragma unroll 8
    for (int k4 = 0; k4 < 64; ++k4) {
      float4 a = *(const float4*)&wk_s[m * KST + k4 * 4];
      float4 b = *(const float4*)&q_s[bh * KST + k4 * 4];
      acc += a.x * b.x + a.y * b.y + a.z * b.z + a.w * b.w;
    }
    __syncthreads();
  }
  kk[(size_t)bh * 1024 + m0 + m] = 1.f / (1.f + __expf(-acc));
}

// ---------------- vgemm: ov = bf16( (emb_bf @ Wv^T) * gate ) ----------------
// M=8192, N=256, K=256. Tile 64x64, single-shot K (whole panel in LDS, ONE barrier).
// grid (4,128), 2 blocks/CU; 16 independent 16B loads in flight per thread.
#define VST 264
__global__ __launch_bounds__(256) void vgemm_kernel(
    const unsigned short* __restrict__ Abf, const unsigned short* __restrict__ Wvb,
    const float* __restrict__ kk, unsigned short* __restrict__ ov) {
  __shared__ __align__(16) unsigned short Vs[128 * VST];  // 67584 B
  const int nt = blockIdx.x, mt = blockIdx.y;
  const int m0 = mt * 64, n0 = nt * 64;
  const int t = threadIdx.x;
  const int wave = t >> 6, lane = t & 63;
  const int wr = wave >> 1, wc = wave & 1;
  const int lr = lane & 15, lq = lane >> 4;

  const int row0 = t >> 5, kb = t & 31;  // slot: row = row0 + i*8, 16B unit kb
#pragma unroll
  for (int i = 0; i < 8; ++i)
    *(short8*)&Vs[(row0 + i * 8) * VST + kb * 8] =
        *(const short8*)(Abf + (size_t)(m0 + row0 + i * 8) * 256 + kb * 8);
#pragma unroll
  for (int i = 0; i < 8; ++i)
    *(short8*)&Vs[(64 + row0 + i * 8) * VST + kb * 8] =
        *(const short8*)(Wvb + (size_t)(n0 + row0 + i * 8) * 256 + kb * 8);
  __syncthreads();

  f32x4 acc[2][2];
#pragma unroll
  for (int i = 0; i < 2; ++i)
#pragma unroll
    for (int j = 0; j < 2; ++j) acc[i][j] = f32x4{0.f, 0.f, 0.f, 0.f};

#pragma unroll
  for (int kc = 0; kc < 8; ++kc) {
    short8 a0 = *(const short8*)&Vs[(wr * 32 + lr) * VST + kc * 32 + lq * 8];
    short8 a1 = *(const short8*)&Vs[(wr * 32 + 16 + lr) * VST + kc * 32 + lq * 8];
    short8 b0 = *(const short8*)&Vs[(64 + wc * 32 + lr) * VST + kc * 32 + lq * 8];
    short8 b1 = *(const short8*)&Vs[(64 + wc * 32 + 16 + lr) * VST + kc * 32 + lq * 8];
    acc[0][0] = __builtin_amdgcn_mfma_f32_16x16x32_bf16(a0, b0, acc[0][0], 0, 0, 0);
    acc[0][1] = __builtin_amdgcn_mfma_f32_16x16x32_bf16(a0, b1, acc[0][1], 0, 0, 0);
    acc[1][0] = __builtin_amdgcn_mfma_f32_16x16x32_bf16(a1, b0, acc[1][0], 0, 0, 0);
    acc[1][1] = __builtin_amdgcn_mfma_f32_16x16x32_bf16(a1, b1, acc[1][1], 0, 0, 0);
  }

#pragma unroll
  for (int mi = 0; mi < 2; ++mi)
#pragma unroll
    for (int ni = 0; ni < 2; ++ni) {
      int col = n0 + wc * 32 + ni * 16 + lr;
      int h = col >> 6;
      int rbase = m0 + wr * 32 + mi * 16 + lq * 4;
#pragma unroll
      for (int r2 = 0; r2 < 4; ++r2) {
        int row = rbase + r2;
        int bn = row >> 10, n = row & 1023;
        float g = kk[(size_t)(bn * 4 + h) * 1024 + n];
        ov[(size_t)row * 256 + col] = f2bf(acc[mi][ni][r2] * g);
      }
    }
}

// ---------------- GEMM2: out = ov @ Wout^T + b_out, folded, coalesced ----------------
// M=8192, N=4096, K=256. Tile 64x128, grid (32,128). Reg-prefetch double-buffered
// K-pipeline (4 tiles, fully peeled), LDS 55KB -> 2 blocks/CU. LDS-transposed epilogue.
#define CST 132  // epilogue C_s stride (floats)
struct StageG2 { short8 a[2]; short8 b[4]; };

__device__ __forceinline__ void g2_load(StageG2& s, const unsigned short* pA,
                                        const unsigned short* pB, int k0) {
#pragma unroll
  for (int i = 0; i < 2; ++i)
    s.a[i] = *(const short8*)(pA + (size_t)i * 32 * 256 + k0);
#pragma unroll
  for (int i = 0; i < 4; ++i)
    s.b[i] = *(const short8*)(pB + (size_t)i * 32 * 256 + k0);
}
__device__ __forceinline__ void g2_write(unsigned short* Ab, unsigned short* Bb,
                                         int dA, int dB, const StageG2& s) {
#pragma unroll
  for (int i = 0; i < 2; ++i) *(short8*)&Ab[dA + i * 32 * LDA] = s.a[i];
#pragma unroll
  for (int i = 0; i < 4; ++i) *(short8*)&Bb[dB + i * 32 * LDA] = s.b[i];
}

__global__ __launch_bounds__(256, 2) void gemm2_out(
    const unsigned short* __restrict__ Abf, const unsigned short* __restrict__ Wob,
    const float* __restrict__ b_out, float* __restrict__ out) {
  __shared__ __align__(16) unsigned short smbuf[2][192 * LDA];  // 55296 B
  float* csm = (float*)&smbuf[0][0];                            // epilogue aliases (33792 B)
  const int nt = blockIdx.x, mt = blockIdx.y;
  const int m0 = mt * 64, n0 = nt * 128;
  const int t = threadIdx.x;
  const int wave = t >> 6, lane = t & 63;
  const int wm = wave >> 1, wn = wave & 1;
  const int lr = lane & 15, lq = lane >> 4;

  unsigned short* A0 = &smbuf[0][0]; unsigned short* B0 = &smbuf[0][64 * LDA];
  unsigned short* A1 = &smbuf[1][0]; unsigned short* B1 = &smbuf[1][64 * LDA];

  const unsigned short* pA = Abf + (size_t)(m0 + (t >> 3)) * 256 + (t & 7) * 8;
  const unsigned short* pB = Wob + (size_t)(n0 + (t >> 3)) * 256 + (t & 7) * 8;
  const int dA = (t >> 3) * LDA + (t & 7) * 8;
  const int dB = dA;

  f32x4 acc[2][4];
#pragma unroll
  for (int i = 0; i < 2; i++)
#pragma unroll
    for (int j = 0; j < 4; j++) acc[i][j] = f32x4{0.f, 0.f, 0.f, 0.f};

  StageG2 st0, st1;
  g2_load(st0, pA, pB, 0);
  g2_load(st1, pA, pB, 64);
  g2_write(A0, B0, dA, dB, st0);
  __syncthreads();
  g2_load(st0, pA, pB, 128);
  mfma_tile(A0, B0, wm, wn, lr, lq, acc);
  g2_write(A1, B1, dA, dB, st1);
  __syncthreads();
  g2_load(st1, pA, pB, 192);
  mfma_tile(A1, B1, wm, wn, lr, lq, acc);
  g2_write(A0, B0, dA, dB, st0);
  __syncthreads();
  mfma_tile(A0, B0, wm, wn, lr, lq, acc);
  g2_write(A1, B1, dA, dB, st1);
  __syncthreads();
  mfma_tile(A1, B1, wm, wn, lr, lq, acc);
  __syncthreads();  // all reads done before epilogue aliases LDS

  // stage C tile into LDS [m_local][p_local]
#pragma unroll
  for (int mi = 0; mi < 2; ++mi)
#pragma unroll
    for (int ni = 0; ni < 4; ++ni) {
      int pl = wn * 64 + ni * 16 + lr;
      int mb = wm * 32 + mi * 16 + lq * 4;
#pragma unroll
      for (int r2 = 0; r2 < 4; ++r2)
        csm[(mb + r2) * CST + pl] = acc[mi][ni][r2];
    }
  __syncthreads();
  // coalesced folded write: tile = 2 contiguous 16 KiB runs (one per c2)
  const int bn = m0 >> 10;
  const int ph0 = (m0 & 1023) >> 5;
  const int c0 = n0 >> 6;
#pragma unroll
  for (int i = 0; i < 8; ++i) {
    int idx4 = t + i * 256;                  // 0..2047 float4s
    int kw4 = idx4 & 1;
    int pw = (idx4 >> 1) & 31;
    int kh = (idx4 >> 6) & 7;
    int c2 = (idx4 >> 9) & 1;
    int ph = (idx4 >> 10) & 1;
    int m_local = ph * 32 + pw;
    int p_local = c2 * 64 + kh * 8 + kw4 * 4;
    float4 v = *(const float4*)&csm[m_local * CST + p_local];
    float4 bo = *(const float4*)(b_out + n0 + p_local);
    v.x += bo.x; v.y += bo.y; v.z += bo.z; v.w += bo.w;
    size_t addr = ((size_t)((bn << 6) + c0 + c2) << 16) +
                  (size_t)(((ph0 + ph) << 3) + kh) * 256 + (pw << 3) + kw4 * 4;
    *(float4*)(out + addr) = v;
  }
}

extern "C" void kernel_launch(void* const* d_in, const int* in_sizes, int n_in,
                              void* d_out, int out_size, void* d_ws, size_t ws_size,
                              hipStream_t stream) {
  const float* x       = (const float*)d_in[0];
  const float* W_embed = (const float*)d_in[1];
  const float* b_embed = (const float*)d_in[2];
  const float* pos     = (const float*)d_in[3];
  const float* Wq      = (const float*)d_in[4];
  const float* Wk      = (const float*)d_in[5];
  const float* Wv      = (const float*)d_in[6];
  const float* Wout    = (const float*)d_in[7];
  const float* b_out   = (const float*)d_in[8];
  float* out = (float*)d_out;

  char* ws = (char*)d_ws;
  const size_t MB = 1024 * 1024;
  unsigned short* emb_bf = (unsigned short*)(ws);             // 4 MiB
  unsigned short* ov     = (unsigned short*)(ws + 4 * MB);    // 4 MiB
  unsigned short* Wb     = (unsigned short*)(ws + 8 * MB);    // 2 MiB
  unsigned short* Wob    = (unsigned short*)(ws + 10 * MB);   // 2 MiB
  unsigned short* Wvb    = (unsigned short*)(ws + 12 * MB);   // 128 KiB
  float* q               = (float*)(ws + 12 * MB + 131072);   // 128 KiB
  float* kk              = (float*)(ws + 12 * MB + 262144);   // 128 KiB
  float* WqR             = (float*)(ws + 12 * MB + 393216);   // 4 KiB

  prep_kernel<<<2116, 256, 0, stream>>>(W_embed, Wout, Wv, Wq, Wb, Wob, Wvb, WqR);
  gemm1_fused<<<256, 256, 0, stream>>>(x, Wb, b_embed, pos, WqR, emb_bf, q);
  k_kernel<<<128, 256, 0, stream>>>(q, Wk, kk);
  vgemm_kernel<<<dim3(4, 128), 256, 0, stream>>>(emb_bf, Wvb, kk, ov);
  gemm2_out<<<dim3(32, 128), 256, 0, stream>>>(ov, Wob, b_out, out);
}